// Round 3
// baseline (807.455 us; speedup 1.0000x reference)
//
#include <hip/hip_runtime.h>
#include <hip/hip_bf16.h>

// RecNN: u = relu(contents @ W_u^T + b_u); v = u[internal] @ W_hu^T (hoisted);
// 10 levels emb = relu([emb_L|emb_R] @ W_LR^T + v + b_h).
//
// Round-7 structure: 128x256 tile, 512 threads (8 waves 2x4, wave 64x64,
// acc[4][4]) -- round-6 geometry -- plus the T3/T4 deep pipeline: THREE-slot
// LDS rotation, stage k+2 issued right after the barrier of step k, counted
// s_waitcnt vmcnt(3) (one 3-op stage group stays in flight ACROSS the
// barrier; never drain to 0 in the loop). Round 5 showed this schedule
// spills if MODE 0 reg-stages fp32 A, so contents is pre-converted to bf16
// by a streaming kernel and ALL gemm modes stage exactly 3 uniform
// global_load_lds ops per k-step. Keeps the validated XOR granule swizzle
// (source-preswizzled for linear glds, same XOR on ds_read; conflicts 0)
// and the XCD swizzle.

typedef unsigned short u16;
typedef __attribute__((ext_vector_type(8))) short bf16x8;
typedef __attribute__((ext_vector_type(4))) float f32x4;

#define BK 32

__device__ __forceinline__ u16 f2b(float f) {
  union { float f; unsigned u; } c; c.f = f;
  unsigned u = c.u;
  return (u16)((u + 0x7fffu + ((u >> 16) & 1u)) >> 16);  // RNE
}

__device__ __forceinline__ float b2f(unsigned hi16) {
  union { float f; unsigned u; } c; c.u = hi16 << 16; return c.f;
}

__device__ __forceinline__ void glds16(const void* g, void* l) {
  __builtin_amdgcn_global_load_lds(
      (__attribute__((address_space(1))) void*)g,
      (__attribute__((address_space(3))) void*)l, 16, 0, 0);
}

// Counted wait + raw barrier. lgkmcnt(0) before the barrier makes
// stage-after-barrier race-free: every wave's ds_reads of the previous
// step are retired before anyone passes, so the slot about to be
// overwritten (current+2 == current-1 mod 3) is dead in all waves.
template <int N>
__device__ __forceinline__ void wait_barrier() {
  asm volatile("s_waitcnt vmcnt(%0) lgkmcnt(0)" :: "n"(N) : "memory");
  __builtin_amdgcn_s_barrier();
  asm volatile("" ::: "memory");
}

// MODE 0: A flat bf16 [M][K], epilogue bias+relu                 (GEMM1)
// MODE 2: A flat bf16 [M][K], raw store                          (v-GEMM)
// MODE 1: A gathered [emb[c.x] | emb[c.y]] (K=1024), +v+bias+relu (levels)
template <int MODE>
__global__ __launch_bounds__(512, 2)
void gemm_db(const u16* __restrict__ Abf,
             const u16* __restrict__ embPrev,
             const int2* __restrict__ idx,
             const u16* __restrict__ vLvl,   // [M][512] bf16
             const u16* __restrict__ W,      // bf16, row stride ldb (B^T)
             int ldb,
             const float* __restrict__ bias,
             u16* __restrict__ out,          // [M][512] bf16
             int M, int K, int nBlkM) {
  __shared__ __align__(16) u16 lA[3][128 * BK];   // 3 x 8 KB
  __shared__ __align__(16) u16 lB[3][256 * BK];   // 3 x 16 KB

  const int tid  = threadIdx.x;
  const int lane = tid & 63;
  const int wv   = tid >> 6;                 // 0..7
  const int wrow = wv >> 2, wcol = wv & 3;   // 2 x 4 wave grid

  // XCD swizzle: the 2 n-blocks of one m-block -> same XCD (b%8).
  int mb, nb;
  {
    int b = blockIdx.x;
    if ((nBlkM & 7) == 0) {
      int xcd = b & 7;
      nb = (b >> 3) & 1;
      mb = ((b >> 4) << 3) | xcd;
    } else { nb = b & 1; mb = b >> 1; }
  }
  const int mBase = mb * 128;
  const int n0    = nb * 256;

  const int rowA0 = tid >> 2;                // 0..127 (one A row / thread)
  // Source-preswizzled column granule (8 elems = one 16B glds granule):
  // physical granule (tid&3) of row r holds logical granule
  // (tid&3) ^ ((r>>1)&3); (r>>1)&3 == (tid>>3)&3.
  const int colq  = ((tid & 3) ^ ((tid >> 3) & 3)) * 8;

  const u16 *ab0 = nullptr, *aL0 = nullptr, *aR0 = nullptr;
  {
    int m0 = min(mBase + rowA0, M - 1);
    if (MODE != 1) {
      ab0 = Abf + (size_t)m0 * K + colq;
    } else {
      int2 c0 = idx[m0];
      aL0 = embPrev + (size_t)c0.x * 512 + colq;
      aR0 = embPrev + (size_t)c0.y * 512 + colq;
    }
  }
  const u16* bp0 = W + (size_t)(n0 + rowA0) * ldb + colq;        // B rows 0..127
  const u16* bp1 = bp0 + (size_t)128 * ldb;                      // B rows 128..255

  f32x4 acc[4][4] = {};
  const int fm  = lane & 15;
  // Read-side swizzle: logical granule g=lane>>4 of row r lives at
  // g ^ ((r>>1)&3), and (r>>1)&3 == (fm>>1)&3 (row offsets are x16).
  const int gs8 = ((lane >> 4) ^ ((fm >> 1) & 3)) * 8;
  const int nk  = K / BK;

  // Exactly 3 vmem ops per stage group, in every mode.
  auto stage = [&](int buf, int k0) {
    if (MODE != 1) {
      glds16(ab0 + k0, &lA[buf][tid * 8]);
    } else {  // gather; colq < 32 elems never flips the L/R bit
      const u16* g0 = ((k0 & 512) ? aR0 : aL0) + (k0 & 511);
      glds16(g0, &lA[buf][tid * 8]);
    }
    glds16(bp0 + k0, &lB[buf][tid * 8]);
    glds16(bp1 + k0, &lB[buf][(tid + 512) * 8]);
  };
  auto compute = [&](int buf) {
    bf16x8 av[4], bv[4];
#pragma unroll
    for (int i = 0; i < 4; i++) {
      av[i] = *(const bf16x8*)&lA[buf][(wrow * 64 + i * 16 + fm) * BK + gs8];
      bv[i] = *(const bf16x8*)&lB[buf][(wcol * 64 + i * 16 + fm) * BK + gs8];
    }
    __builtin_amdgcn_s_setprio(1);
#pragma unroll
    for (int i = 0; i < 4; i++)
#pragma unroll
      for (int j = 0; j < 4; j++)
        acc[i][j] = __builtin_amdgcn_mfma_f32_16x16x32_bf16(av[i], bv[j], acc[i][j], 0, 0, 0);
    __builtin_amdgcn_s_setprio(0);
  };

  // --- prologue: slots 0 and 1 in flight ---
  stage(0, 0);
  asm volatile("" ::: "memory");      // group boundary
  stage(1, BK);

  // --- main loop: depth-2 prefetch, counted vmcnt (one group in flight) ---
  int sl = 0;
  for (int ks = 0; ks < nk - 2; ks++) {
    wait_barrier<3>();                // slot ks complete; slot ks+1 in flight
    int s1 = sl + 1; if (s1 == 3) s1 = 0;
    int s2 = s1 + 1; if (s2 == 3) s2 = 0;
    stage(s2, (ks + 2) * BK);         // in flight for ~2 steps
    compute(sl);
    sl = s1;
  }
  {                                   // ks = nk-2: nothing left to stage
    wait_barrier<3>();
    int s1 = sl + 1; if (s1 == 3) s1 = 0;
    compute(sl);
    sl = s1;
  }
  wait_barrier<0>();                  // ks = nk-1: drain
  compute(sl);

  // Epilogue: C/D layout col=lane&15, row=(lane>>4)*4+reg (m89-verified).
  const int r0 = (lane >> 4) * 4;
#pragma unroll
  for (int i = 0; i < 4; i++) {
    int mI = mBase + wrow * 64 + i * 16 + r0;
#pragma unroll
    for (int j = 0; j < 4; j++) {
      int col = n0 + wcol * 64 + j * 16 + fm;
      float bb = (MODE == 2) ? 0.f : bias[col];
#pragma unroll
      for (int r = 0; r < 4; r++) {
        int m = mI + r;
        if (m < M) {
          float v = acc[i][j][r] + bb;
          if (MODE == 1) v += b2f(vLvl[(size_t)m * 512 + col]);
          if (MODE != 2) v = v > 0.f ? v : 0.f;
          out[(size_t)m * 512 + col] = f2b(v);
        }
      }
    }
  }
}

// Streaming fp32 -> bf16 (8 elems / thread / iter, grid-stride).
__global__ void cvt_f32_bf16(const float* __restrict__ src,
                             u16* __restrict__ dst, int n8) {
  int stride = gridDim.x * blockDim.x;
  for (int i = blockIdx.x * blockDim.x + threadIdx.x; i < n8; i += stride) {
    const float4* s = (const float4*)(src + (size_t)i * 8);
    float4 a = s[0], b = s[1];
    union { u16 u[8]; bf16x8 v; } o;
    o.u[0] = f2b(a.x); o.u[1] = f2b(a.y); o.u[2] = f2b(a.z); o.u[3] = f2b(a.w);
    o.u[4] = f2b(b.x); o.u[5] = f2b(b.y); o.u[6] = f2b(b.z); o.u[7] = f2b(b.w);
    *(bf16x8*)(dst + (size_t)i * 8) = o.v;
  }
}

// One launch: convert W_u (512x256) and W_h (512x1536) fp32 -> bf16.
__global__ void cvt_weights(const float* __restrict__ Wu,
                            const float* __restrict__ Wh,
                            u16* __restrict__ Wub, u16* __restrict__ Whb) {
  const int nWu = 512 * 256 / 8;
  const int nWh = 512 * 1536 / 8;
  int i = blockIdx.x * blockDim.x + threadIdx.x;
  const float* src; u16* dst; int c;
  if (i < nWu) { src = Wu; dst = Wub; c = i; }
  else if (i < nWu + nWh) { src = Wh; dst = Whb; c = i - nWu; }
  else return;
  const float4* s = (const float4*)(src + (size_t)c * 8);
  float4 a = s[0], b = s[1];
  union { u16 u[8]; bf16x8 v; } o;
  o.u[0] = f2b(a.x); o.u[1] = f2b(a.y); o.u[2] = f2b(a.z); o.u[3] = f2b(a.w);
  o.u[4] = f2b(b.x); o.u[5] = f2b(b.y); o.u[6] = f2b(b.z); o.u[7] = f2b(b.w);
  *(bf16x8*)(dst + (size_t)c * 8) = o.v;
}

__global__ void cvt_bf16_to_f32(const u16* __restrict__ src, float* __restrict__ dst, int n4) {
  int i = blockIdx.x * blockDim.x + threadIdx.x;
  if (i >= n4) return;
  uint2 p = ((const uint2*)src)[i];
  float4 o;
  o.x = b2f(p.x & 0xffffu); o.y = b2f(p.x >> 16);
  o.z = b2f(p.y & 0xffffu); o.w = b2f(p.y >> 16);
  ((float4*)dst)[i] = o;
}

extern "C" void kernel_launch(void* const* d_in, const int* in_sizes, int n_in,
                              void* d_out, int out_size, void* d_ws, size_t ws_size,
                              hipStream_t stream) {
  const float* contents = (const float*)d_in[0];
  const int2*  children = (const int2*)d_in[1];
  const float* W_u = (const float*)d_in[2];
  const float* b_u = (const float*)d_in[3];
  const float* W_h = (const float*)d_in[4];
  const float* b_h = (const float*)d_in[5];
  float* out = (float*)d_out;

  const int B = 64, D = 11, F = 256, H = 512;
  const int N = B * ((1 << D) - 1);            // 131008
  const int NI = B * ((1 << (D - 1)) - 1);     // 65472

  // Workspace (u16 elems): u_bf [N*512] | Wub | Whb | R.
  // R (size N*256 >= NI*512) holds cont_bf until GEMM1 finishes, then v_bf
  // (cont_bf is dead once u is computed; v-GEMM writes v over it).
  u16* ws16 = (u16*)d_ws;
  u16* u_bf = ws16;
  u16* Wub  = u_bf + (size_t)N * H;
  u16* Whb  = Wub + 512 * 256;
  u16* R    = Whb + 512 * 1536;
  u16* cont_bf = R;
  u16* v_bf    = R;
  u16* embA = u_bf;                            // level-9 dst (32768 rows)
  u16* embB = u_bf + (size_t)32768 * 512;

  // --- weight conversion (single tiny launch) ---
  {
    int n = (512 * 256 + 512 * 1536) / 8;
    cvt_weights<<<(n + 255) / 256, 256, 0, stream>>>(W_u, W_h, Wub, Whb);
  }

  // --- contents fp32 -> bf16 (streaming) ---
  {
    int n8 = N * F / 8;                        // 4,192,256
    cvt_f32_bf16<<<2048, 256, 0, stream>>>(contents, cont_bf, n8);
  }

  // --- GEMM1: u = relu(cont_bf @ W_u^T + b_u) ---
  {
    int mb = (N + 127) / 128;                  // 1024
    gemm_db<0><<<mb * 2, 512, 0, stream>>>(cont_bf, nullptr, nullptr,
                                           nullptr, Wub, F, b_u, u_bf, N, F, mb);
  }

  // --- v-GEMM: v = u[0:NI] @ W_hu^T (W_h cols 1024..1535 in place) ---
  {
    int mb = (NI + 127) / 128;                 // 512
    gemm_db<2><<<mb * 2, 512, 0, stream>>>(u_bf, nullptr, nullptr,
                                           nullptr, Whb + 1024, 3 * H, nullptr,
                                           v_bf, NI, H, mb);
  }

  // --- tree levels j = D-2 .. 0 (K=1024 children; v in epilogue) ---
  const u16* embPrev = u_bf + (size_t)NI * H;  // leaves = u[NI:]
  u16* dst = embA;
  for (int j = D - 2; j >= 0; --j) {
    int M = B << j;
    int o = B * ((1 << j) - 1);
    int mb = (M + 127) / 128;
    gemm_db<1><<<mb * 2, 512, 0, stream>>>(nullptr, embPrev,
                                           children + o, v_bf + (size_t)o * H,
                                           Whb, 3 * H, b_h, dst, M, 2 * H, mb);
    embPrev = dst;
    dst = (dst == embA) ? embB : embA;
  }

  // --- level-0 emb (64 x 512) -> fp32 output ---
  {
    int n4 = B * H / 4;
    cvt_bf16_to_f32<<<(n4 + 255) / 256, 256, 0, stream>>>(embPrev, out, n4);
  }
}

// Round 4
// 597.744 us; speedup vs baseline: 1.3508x; 1.3508x over previous
//
#include <hip/hip_runtime.h>
#include <hip/hip_bf16.h>

// RecNN: u = relu(contents @ W_u^T + b_u); v = u[internal] @ W_hu^T (hoisted);
// 10 levels emb = relu([emb_L|emb_R] @ W_LR^T + v + b_h).
//
// Round-8 = Round-4 base (best total: 693 us; 128x128 tile, 4 waves, BK=32,
// simple 2-buffer one-__syncthreads-per-step schedule, fused fp32->bf16 A
// staging) + two evidence-backed deltas:
//  (1) XOR granule swizzle on the k-loop LDS (validated: bank conflicts
//      4.19M -> 0). Linear glds dest + preswizzled SOURCE granule; MODE-0
//      A applies the same XOR on its ds_write address; reads XOR the
//      fragment granule.
//  (2) Coalesced epilogue. R4-R7 all plateaued at ~1.15-1.2 TB/s write
//      throughput with nothing else saturated: the C-fragment store pattern
//      (4x32B segments/instr, 16 scalar u16 stores/thread) is write-path
//      bound. New epilogue transposes each 16x64 wave slab through a
//      per-wave LDS region and stores bf16x8 full 128-B lines; vLvl/bias
//      reads become wide loads in the same pattern.

typedef unsigned short u16;
typedef __attribute__((ext_vector_type(8))) short bf16x8;
typedef __attribute__((ext_vector_type(4))) float f32x4;
typedef __attribute__((ext_vector_type(2))) float f32x2;

#define BK 32

__device__ __forceinline__ u16 f2b(float f) {
  union { float f; unsigned u; } c; c.f = f;
  unsigned u = c.u;
  return (u16)((u + 0x7fffu + ((u >> 16) & 1u)) >> 16);  // RNE
}

__device__ __forceinline__ float b2f(unsigned hi16) {
  union { float f; unsigned u; } c; c.u = hi16 << 16; return c.f;
}

__device__ __forceinline__ void glds16(const void* g, void* l) {
  __builtin_amdgcn_global_load_lds(
      (__attribute__((address_space(1))) void*)g,
      (__attribute__((address_space(3))) void*)l, 16, 0, 0);
}

// MODE 0: A fp32 [M][K] (reg-staged + cvt in-loop), epilogue bias+relu (GEMM1)
// MODE 2: A bf16 [M][K], raw store                                    (v-GEMM)
// MODE 1: A gathered [emb[c.x] | emb[c.y]] (K=1024), +v+bias+relu     (levels)
template <int MODE>
__global__ __launch_bounds__(256, 3)
void gemm_db(const float* __restrict__ Af32,
             const u16* __restrict__ Abf,
             const u16* __restrict__ embPrev,
             const int2* __restrict__ idx,
             const u16* __restrict__ vLvl,   // [M][512] bf16
             const u16* __restrict__ W,      // bf16, row stride ldb (B^T)
             int ldb,
             const float* __restrict__ bias,
             u16* __restrict__ out,          // [M][512] bf16
             int M, int K, int nBlkM) {
  __shared__ __align__(16) u16 lA[2][128 * BK];   // 2 x 8 KB
  __shared__ __align__(16) u16 lB[2][128 * BK];   // 2 x 8 KB
  __shared__ __align__(16) float ep[4][16 * 66];  // 16.5 KB epilogue transpose

  const int tid  = threadIdx.x;
  const int lane = tid & 63;
  const int wv   = tid >> 6;
  const int wrow = wv >> 1, wcol = wv & 1;

  // XCD swizzle: 4 n-blocks of one m-block -> same XCD (b%8), adjacent in
  // dispatch order, so A re-reads hit that XCD's L2.
  int mb, nb;
  {
    int b = blockIdx.x;
    if ((nBlkM & 7) == 0) {
      int xcd = b & 7;
      nb = (b >> 3) & 3;
      mb = ((b >> 5) << 3) | xcd;
    } else { nb = b & 3; mb = b >> 2; }
  }
  const int mBase = mb * 128;
  const int n0    = nb * 128;

  const int rowA0 = tid >> 2;       // 0..63 (round 0; +64 for round 1)
  const int q     = tid & 3;
  const int colqG = q * 8;          // unswizzled (MODE-0 fp32 register loads)
  // Source-preswizzled granule: physical granule (tid&3) of row r holds
  // logical granule (tid&3) ^ ((r>>1)&3); (r>>1)&3 == (tid>>3)&3 and is
  // identical for the +64 row.
  const int colq  = (q ^ ((tid >> 3) & 3)) * 8;

  const float *af0 = nullptr, *af1 = nullptr;
  const u16 *ab0 = nullptr, *ab1 = nullptr;
  const u16 *aL0 = nullptr, *aR0 = nullptr, *aL1 = nullptr, *aR1 = nullptr;
  {
    int m0 = min(mBase + rowA0, M - 1);
    int m1 = min(mBase + rowA0 + 64, M - 1);
    if (MODE == 0) {
      af0 = Af32 + (size_t)m0 * K;
      af1 = Af32 + (size_t)m1 * K;
    } else if (MODE == 2) {
      ab0 = Abf + (size_t)m0 * K + colq;
      ab1 = Abf + (size_t)m1 * K + colq;
    } else {
      int2 c0 = idx[m0], c1 = idx[m1];
      aL0 = embPrev + (size_t)c0.x * 512 + colq;
      aR0 = embPrev + (size_t)c0.y * 512 + colq;
      aL1 = embPrev + (size_t)c1.x * 512 + colq;
      aR1 = embPrev + (size_t)c1.y * 512 + colq;
    }
  }
  const u16* bp0 = W + (size_t)(n0 + rowA0) * ldb + colq;
  const u16* bp1 = W + (size_t)(n0 + rowA0 + 64) * ldb + colq;

  f32x4 acc[4][4] = {};
  const int fm  = lane & 15;
  // Read-side swizzle: logical granule g=lane>>4 of row r lives at
  // g ^ ((r>>1)&3); for fragment rows (..+fm) that is (fm>>1)&3.
  const int gs8 = ((lane >> 4) ^ ((fm >> 1) & 3)) * 8;
  const int nk  = K / BK;

  auto stageB = [&](int buf, int k0) {
    glds16(bp0 + k0, &lB[buf][tid * 8]);
    glds16(bp1 + k0, &lB[buf][(tid + 256) * 8]);
  };
  auto stageA_bf = [&](int buf, int k0) {
    if (MODE == 2) {
      glds16(ab0 + k0, &lA[buf][tid * 8]);
      glds16(ab1 + k0, &lA[buf][(tid + 256) * 8]);
    } else {  // MODE 1 gather; colq < 32 elems never flips the L/R bit
      const u16* g0 = ((k0 & 512) ? aR0 : aL0) + (k0 & 511);
      const u16* g1 = ((k0 & 512) ? aR1 : aL1) + (k0 & 511);
      glds16(g0, &lA[buf][tid * 8]);
      glds16(g1, &lA[buf][(tid + 256) * 8]);
    }
  };
  // MODE-0 A: register-staged fp32 -> cvt -> ds_write at the SWIZZLED
  // granule so the read-side XOR matches.
  auto cvtwrite = [&](int buf, float4 x, float4 y, int slot) {
    union { __hip_bfloat162 h[4]; bf16x8 v; } o;
    o.h[0] = __float22bfloat162_rn({x.x, x.y});
    o.h[1] = __float22bfloat162_rn({x.z, x.w});
    o.h[2] = __float22bfloat162_rn({y.x, y.y});
    o.h[3] = __float22bfloat162_rn({y.z, y.w});
    int off = ((slot >> 2) * 4 + ((slot & 3) ^ ((slot >> 3) & 3))) * 8;
    *(bf16x8*)&lA[buf][off] = o.v;
  };

  // --- prologue: stage k-step 0 into buffer 0 ---
  if (MODE == 0) {
    const float4* s0 = (const float4*)(af0 + colqG);
    const float4* s1 = (const float4*)(af1 + colqG);
    cvtwrite(0, s0[0], s0[1], tid);
    cvtwrite(0, s1[0], s1[1], tid + 256);
    stageB(0, 0);
  } else {
    stageA_bf(0, 0);
    stageB(0, 0);
  }

  for (int ks = 0; ks < nk; ks++) {
    const int cur = ks & 1, nxt = cur ^ 1;
    __syncthreads();                 // cur buffer complete (vmcnt+lgkm drained)
    const bool more = (ks + 1 < nk);
    float4 x0, y0, x1, y1;
    if (more) {
      const int k1 = (ks + 1) * BK;
      if (MODE == 0) {               // issue loads now, convert after MFMA
        const float4* s0 = (const float4*)(af0 + k1 + colqG);
        const float4* s1 = (const float4*)(af1 + k1 + colqG);
        x0 = s0[0]; y0 = s0[1]; x1 = s1[0]; y1 = s1[1];
      } else {
        stageA_bf(nxt, k1);
      }
      stageB(nxt, k1);               // in flight during the MFMA stage below
    }

    bf16x8 av[4], bv[4];
#pragma unroll
    for (int i = 0; i < 4; i++) {
      av[i] = *(const bf16x8*)&lA[cur][(wrow * 64 + i * 16 + fm) * BK + gs8];
      bv[i] = *(const bf16x8*)&lB[cur][(wcol * 64 + i * 16 + fm) * BK + gs8];
    }
#pragma unroll
    for (int i = 0; i < 4; i++)
#pragma unroll
      for (int j = 0; j < 4; j++)
        acc[i][j] = __builtin_amdgcn_mfma_f32_16x16x32_bf16(av[i], bv[j], acc[i][j], 0, 0, 0);

    if (MODE == 0 && more) {         // convert + LDS-write after MFMA issued
      cvtwrite(nxt, x0, y0, tid);
      cvtwrite(nxt, x1, y1, tid + 256);
    }
  }

  // ---- epilogue: per-wave transpose through LDS, full-line b128 stores ----
  // acc[i][j][r] = C(row = wrow*64 + i*16 + r0 + r, col = wcol*64 + j*16 + fm).
  // Per i-pass: scatter the 16x64 slab into ep[wv] (row-major, stride 66:
  // write banks 2-way-free), then each lane reads 8 consecutive f32 of one
  // row and stores one bf16x8 => per store instr 8 rows x 128 B full lines.
  const int r0  = (lane >> 4) * 4;
  const int err = lane >> 3;          // 0..7
  const int eg  = lane & 7;           // 8-col granule
  float* epw = ep[wv];
#pragma unroll
  for (int i = 0; i < 4; i++) {
#pragma unroll
    for (int j = 0; j < 4; j++)
#pragma unroll
      for (int r = 0; r < 4; r++)
        epw[(r0 + r) * 66 + j * 16 + fm] = acc[i][j][r];
    // Cross-lane through LDS within the wave: drain DS, pin the schedule.
    asm volatile("s_waitcnt lgkmcnt(0)" ::: "memory");
    __builtin_amdgcn_sched_barrier(0);
#pragma unroll
    for (int s = 0; s < 2; s++) {
      const int rr  = err + s * 8;
      const int m   = mBase + wrow * 64 + i * 16 + rr;
      const int col = n0 + wcol * 64 + eg * 8;
      float p[8];
#pragma unroll
      for (int h = 0; h < 4; h++) {
        f32x2 t = *(const f32x2*)&epw[rr * 66 + eg * 8 + 2 * h];
        p[2 * h]     = t[0];
        p[2 * h + 1] = t[1];
      }
      if (m < M) {
        float bb[8];
        if (MODE != 2) {
          float4 b0v = *(const float4*)(bias + col);
          float4 b1v = *(const float4*)(bias + col + 4);
          bb[0] = b0v.x; bb[1] = b0v.y; bb[2] = b0v.z; bb[3] = b0v.w;
          bb[4] = b1v.x; bb[5] = b1v.y; bb[6] = b1v.z; bb[7] = b1v.w;
        }
        union { u16 u[8]; bf16x8 v; } vl;
        if (MODE == 1) vl.v = *(const bf16x8*)(vLvl + (size_t)m * 512 + col);
        union { u16 u[8]; bf16x8 v; } o;
#pragma unroll
        for (int c = 0; c < 8; c++) {
          float v = p[c];
          if (MODE != 2) v += bb[c];
          if (MODE == 1) v += b2f(vl.u[c]);
          if (MODE != 2) v = v > 0.f ? v : 0.f;
          o.u[c] = f2b(v);
        }
        *(bf16x8*)(out + (size_t)m * 512 + col) = o.v;
      }
    }
    // All lanes finished reading ep before the next i-pass overwrites it
    // (wave-lockstep instruction stream; no cross-wave sharing).
    __builtin_amdgcn_sched_barrier(0);
  }
}

// One launch: convert W_u (512x256) and W_h (512x1536) fp32 -> bf16.
__global__ void cvt_weights(const float* __restrict__ Wu,
                            const float* __restrict__ Wh,
                            u16* __restrict__ Wub, u16* __restrict__ Whb) {
  const int nWu = 512 * 256 / 8;
  const int nWh = 512 * 1536 / 8;
  int i = blockIdx.x * blockDim.x + threadIdx.x;
  const float* src; u16* dst; int c;
  if (i < nWu) { src = Wu; dst = Wub; c = i; }
  else if (i < nWu + nWh) { src = Wh; dst = Whb; c = i - nWu; }
  else return;
  const float4* s = (const float4*)(src + (size_t)c * 8);
  float4 a = s[0], b = s[1];
  union { u16 u[8]; bf16x8 v; } o;
  o.u[0] = f2b(a.x); o.u[1] = f2b(a.y); o.u[2] = f2b(a.z); o.u[3] = f2b(a.w);
  o.u[4] = f2b(b.x); o.u[5] = f2b(b.y); o.u[6] = f2b(b.z); o.u[7] = f2b(b.w);
  *(bf16x8*)(dst + (size_t)c * 8) = o.v;
}

__global__ void cvt_bf16_to_f32(const u16* __restrict__ src, float* __restrict__ dst, int n4) {
  int i = blockIdx.x * blockDim.x + threadIdx.x;
  if (i >= n4) return;
  uint2 p = ((const uint2*)src)[i];
  float4 o;
  o.x = b2f(p.x & 0xffffu); o.y = b2f(p.x >> 16);
  o.z = b2f(p.y & 0xffffu); o.w = b2f(p.y >> 16);
  ((float4*)dst)[i] = o;
}

extern "C" void kernel_launch(void* const* d_in, const int* in_sizes, int n_in,
                              void* d_out, int out_size, void* d_ws, size_t ws_size,
                              hipStream_t stream) {
  const float* contents = (const float*)d_in[0];
  const int2*  children = (const int2*)d_in[1];
  const float* W_u = (const float*)d_in[2];
  const float* b_u = (const float*)d_in[3];
  const float* W_h = (const float*)d_in[4];
  const float* b_h = (const float*)d_in[5];
  float* out = (float*)d_out;

  const int B = 64, D = 11, F = 256, H = 512;
  const int N = B * ((1 << D) - 1);            // 131008
  const int NI = B * ((1 << (D - 1)) - 1);     // 65472

  // Workspace (u16 elems): u_bf [N*512] | v_bf [NI*512] | Wub | Whb.
  // emb ping-pong aliases u's internal rows (dead after the v-GEMM).
  u16* ws16 = (u16*)d_ws;
  u16* u_bf = ws16;
  u16* v_bf = ws16 + (size_t)N * H;
  u16* Wub  = v_bf + (size_t)NI * H;
  u16* Whb  = Wub + 512 * 256;
  u16* embA = u_bf;                            // level-9 dst (32768 rows)
  u16* embB = u_bf + (size_t)32768 * 512;

  // --- weight conversion (single tiny launch) ---
  {
    int n = (512 * 256 + 512 * 1536) / 8;
    cvt_weights<<<(n + 255) / 256, 256, 0, stream>>>(W_u, W_h, Wub, Whb);
  }

  // --- GEMM1: u = relu(contents @ W_u^T + b_u) ---
  {
    int mb = (N + 127) / 128;                  // 1024
    gemm_db<0><<<mb * 4, 256, 0, stream>>>(contents, nullptr, nullptr, nullptr,
                                           nullptr, Wub, F, b_u, u_bf, N, F, mb);
  }

  // --- v-GEMM: v = u[0:NI] @ W_hu^T (W_h cols 1024..1535 in place) ---
  {
    int mb = (NI + 127) / 128;                 // 512
    gemm_db<2><<<mb * 4, 256, 0, stream>>>(nullptr, u_bf, nullptr, nullptr,
                                           nullptr, Whb + 1024, 3 * H, nullptr,
                                           v_bf, NI, H, mb);
  }

  // --- tree levels j = D-2 .. 0 (K=1024 children; v in epilogue) ---
  const u16* embPrev = u_bf + (size_t)NI * H;  // leaves = u[NI:]
  u16* dst = embA;
  for (int j = D - 2; j >= 0; --j) {
    int M = B << j;
    int o = B * ((1 << j) - 1);
    int mb = (M + 127) / 128;
    gemm_db<1><<<mb * 4, 256, 0, stream>>>(nullptr, nullptr, embPrev,
                                           children + o, v_bf + (size_t)o * H,
                                           Whb, 3 * H, b_h, dst, M, 2 * H, mb);
    embPrev = dst;
    dst = (dst == embA) ? embB : embA;
  }

  // --- level-0 emb (64 x 512) -> fp32 output ---
  {
    int n4 = B * H / 4;
    cvt_bf16_to_f32<<<(n4 + 255) / 256, 256, 0, stream>>>(embPrev, out, n4);
  }
}

// Round 5
// 533.315 us; speedup vs baseline: 1.5140x; 1.1208x over previous
//
#include <hip/hip_runtime.h>
#include <hip/hip_bf16.h>

// RecNN: u = relu(contents @ W_u^T + b_u); v = u[internal] @ W_hu^T (hoisted);
// 10 levels emb = relu([emb_L|emb_R] @ W_LR^T + v + b_h).
//
// Round-9 = R8 (best total, coalesced epilogue) + the R7-proven 3-slot
// counted-vmcnt pipeline in ALL modes, with R5/R7's costs removed:
//  - MODE 0 stages fp32 A directly to LDS via global_load_lds (no cvt
//    kernel, no reg staging -> no spill) and converts to bf16 on the
//    fragment-read path (packed cvts hidden under MFMA).
//  - Every mode: uniform glds group per k-step (6 ops MODE0, 4 ops M1/2);
//    stage k+2 right after the barrier of step k; s_waitcnt vmcnt(PEND)
//    keeps one full group in flight ACROSS the barrier (never 0 in-loop).
//  - Epilogue transpose buffer ALIASES the staging LDS (extra barrier
//    before reuse): MODE1/2 LDS stays 48KB+eps -> 3 blocks/CU.
// Swizzles: bf16 tiles keep the validated 16B-granule XOR (conflicts 0);
// fp32 A uses g^(row&7) over 8 granules/row, pre-applied to the glds
// SOURCE (LDS dest must stay lane-linear), matching XOR on ds_read.

typedef unsigned short u16;
typedef __attribute__((ext_vector_type(8))) short bf16x8;
typedef __attribute__((ext_vector_type(4))) float f32x4;
typedef __attribute__((ext_vector_type(2))) float f32x2;

#define BK 32

__device__ __forceinline__ u16 f2b(float f) {
  union { float f; unsigned u; } c; c.f = f;
  unsigned u = c.u;
  return (u16)((u + 0x7fffu + ((u >> 16) & 1u)) >> 16);  // RNE
}

__device__ __forceinline__ float b2f(unsigned hi16) {
  union { float f; unsigned u; } c; c.u = hi16 << 16; return c.f;
}

__device__ __forceinline__ void glds16(const void* g, void* l) {
  __builtin_amdgcn_global_load_lds(
      (__attribute__((address_space(1))) void*)g,
      (__attribute__((address_space(3))) void*)l, 16, 0, 0);
}

// Counted wait + raw barrier. lgkmcnt(0) before the barrier makes
// stage-after-barrier race-free: every wave's ds_reads of the previous
// step retired before anyone passes, so the slot about to be overwritten
// is dead in all waves.
template <int N>
__device__ __forceinline__ void wait_barrier() {
  asm volatile("s_waitcnt vmcnt(%0) lgkmcnt(0)" :: "n"(N) : "memory");
  __builtin_amdgcn_s_barrier();
  asm volatile("" ::: "memory");
}

// MODE 0: A fp32 [M][K] staged to LDS as fp32, cvt on read; bias+relu (GEMM1)
// MODE 2: A bf16 [M][K], raw store                                   (v-GEMM)
// MODE 1: A gathered [emb[c.x] | emb[c.y]] (K=1024), +v+bias+relu    (levels)
template <int MODE>
__global__ __launch_bounds__(256, MODE == 0 ? 2 : 3)
void gemm_db(const float* __restrict__ Af32,
             const u16* __restrict__ Abf,
             const u16* __restrict__ embPrev,
             const int2* __restrict__ idx,
             const u16* __restrict__ vLvl,   // [M][512] bf16
             const u16* __restrict__ W,      // bf16, row stride ldb (B^T)
             int ldb,
             const float* __restrict__ bias,
             u16* __restrict__ out,          // [M][512] bf16
             int M, int K, int nBlkM) {
  constexpr int ASLOT = (MODE == 0) ? 16384 : 8192;   // bytes per A slot
  __shared__ __align__(16) char pool[3 * ASLOT + 3 * 8192];
  auto lAf = [&](int s) { return (float*)(pool + s * ASLOT); };
  auto lAb = [&](int s) { return (u16*)(pool + s * ASLOT); };
  auto lBp = [&](int s) { return (u16*)(pool + 3 * ASLOT + s * 8192); };
  float* ep = (float*)pool;   // epilogue transpose alias (16.9 KB, after sync)

  const int tid  = threadIdx.x;
  const int lane = tid & 63;
  const int wv   = tid >> 6;
  const int wrow = wv >> 1, wcol = wv & 1;

  // XCD swizzle: 4 n-blocks of one m-block -> same XCD (b%8), adjacent in
  // dispatch order, so A re-reads hit that XCD's L2.
  int mb, nb;
  {
    int b = blockIdx.x;
    if ((nBlkM & 7) == 0) {
      int xcd = b & 7;
      nb = (b >> 3) & 3;
      mb = ((b >> 5) << 3) | xcd;
    } else { nb = b & 3; mb = b >> 2; }
  }
  const int mBase = mb * 128;
  const int n0    = nb * 128;

  const int rowA0 = tid >> 2;       // bf16-tile row (round 0; +64 round 1)
  // bf16 source-preswizzled granule (16B = 8 elems): physical granule
  // (tid&3) of row r holds logical (tid&3) ^ ((r>>1)&3); (r>>1)&3 ==
  // (tid>>3)&3, identical for the +64 row.
  const int colq  = ((tid & 3) ^ ((tid >> 3) & 3)) * 8;

  const float* afp[4] = {nullptr, nullptr, nullptr, nullptr};
  const u16 *ab0 = nullptr, *ab1 = nullptr;
  const u16 *aL0 = nullptr, *aR0 = nullptr, *aL1 = nullptr, *aR1 = nullptr;
  if (MODE == 0) {
    // fp32 A: wave wv issue t covers tile rows wv*32+(lane>>3)+t*8,
    // granule (16B = 4 f32) pg = lane&7, logical g = pg ^ (tile_row & 7);
    // (tile_row&7) == (lane>>3)&7 for all t (t*8 doesn't change row&7).
    int rA = wv * 32 + (lane >> 3);
    int gA = ((lane & 7) ^ ((lane >> 3) & 7)) * 4;   // f32 offset in row
#pragma unroll
    for (int t = 0; t < 4; t++) {
      int m0 = min(mBase + rA + t * 8, M - 1);
      afp[t] = Af32 + (size_t)m0 * K + gA;
    }
  } else if (MODE == 2) {
    int m0 = min(mBase + rowA0, M - 1);
    int m1 = min(mBase + rowA0 + 64, M - 1);
    ab0 = Abf + (size_t)m0 * K + colq;
    ab1 = Abf + (size_t)m1 * K + colq;
  } else {
    int m0 = min(mBase + rowA0, M - 1);
    int m1 = min(mBase + rowA0 + 64, M - 1);
    int2 c0 = idx[m0], c1 = idx[m1];
    aL0 = embPrev + (size_t)c0.x * 512 + colq;
    aR0 = embPrev + (size_t)c0.y * 512 + colq;
    aL1 = embPrev + (size_t)c1.x * 512 + colq;
    aR1 = embPrev + (size_t)c1.y * 512 + colq;
  }
  const u16* bp0 = W + (size_t)(n0 + rowA0) * ldb + colq;
  const u16* bp1 = W + (size_t)(n0 + rowA0 + 64) * ldb + colq;

  f32x4 acc[4][4] = {};
  const int fm  = lane & 15;
  const int q   = lane >> 4;
  // bf16 read-side swizzle: logical granule q of row r lives at
  // q ^ ((r>>1)&3); for fragment rows that is (fm>>1)&3.
  const int gs8 = (q ^ ((fm >> 1) & 3)) * 8;
  const int nk  = K / BK;

  // Uniform vmem group per k-step: MODE0 = 4 A-glds + 2 B-glds = 6;
  // MODE1/2 = 2 A + 2 B = 4.
  constexpr int PEND = (MODE == 0) ? 6 : 4;

  auto stage = [&](int s, int k0) {   // k0 in elements (f32 or u16)
    if (MODE == 0) {
      float* d = lAf(s) + (wv * 4) * 256 + lane * 4;
#pragma unroll
      for (int t = 0; t < 4; t++)
        glds16(afp[t] + k0, d + t * 256);
    } else if (MODE == 2) {
      glds16(ab0 + k0, lAb(s) + tid * 8);
      glds16(ab1 + k0, lAb(s) + (tid + 256) * 8);
    } else {  // gather; colq < 32 elems never flips the L/R bit
      const u16* g0 = ((k0 & 512) ? aR0 : aL0) + (k0 & 511);
      const u16* g1 = ((k0 & 512) ? aR1 : aL1) + (k0 & 511);
      glds16(g0, lAb(s) + tid * 8);
      glds16(g1, lAb(s) + (tid + 256) * 8);
    }
    glds16(bp0 + k0, lBp(s) + tid * 8);
    glds16(bp1 + k0, lBp(s) + (tid + 256) * 8);
  };

  auto compute = [&](int s) {
    bf16x8 av[4], bv[4];
    if (MODE == 0) {
      const float* Ab = lAf(s);
#pragma unroll
      for (int i = 0; i < 4; i++) {
        int r  = wrow * 64 + i * 16 + fm;
        int p0 = ((2 * q) ^ (fm & 7)) * 4;        // phys granule, f32 offs
        int p1 = ((2 * q + 1) ^ (fm & 7)) * 4;
        f32x4 a0 = *(const f32x4*)&Ab[r * 32 + p0];   // k = q*8 .. +3
        f32x4 a1 = *(const f32x4*)&Ab[r * 32 + p1];   // k = q*8+4 .. +7
        union { __hip_bfloat162 h[4]; bf16x8 v; } o;
        o.h[0] = __float22bfloat162_rn({a0[0], a0[1]});
        o.h[1] = __float22bfloat162_rn({a0[2], a0[3]});
        o.h[2] = __float22bfloat162_rn({a1[0], a1[1]});
        o.h[3] = __float22bfloat162_rn({a1[2], a1[3]});
        av[i] = o.v;
      }
    } else {
      const u16* Ab = lAb(s);
#pragma unroll
      for (int i = 0; i < 4; i++)
        av[i] = *(const bf16x8*)&Ab[(wrow * 64 + i * 16 + fm) * BK + gs8];
    }
    const u16* Bb = lBp(s);
#pragma unroll
    for (int i = 0; i < 4; i++)
      bv[i] = *(const bf16x8*)&Bb[(wcol * 64 + i * 16 + fm) * BK + gs8];
    __builtin_amdgcn_s_setprio(1);
#pragma unroll
    for (int i = 0; i < 4; i++)
#pragma unroll
      for (int j = 0; j < 4; j++)
        acc[i][j] = __builtin_amdgcn_mfma_f32_16x16x32_bf16(av[i], bv[j], acc[i][j], 0, 0, 0);
    __builtin_amdgcn_s_setprio(0);
  };

  // --- prologue: groups 0 and 1 in flight ---
  stage(0, 0);
  asm volatile("" ::: "memory");      // group boundary
  stage(1, BK);

  // --- main loop: depth-2 prefetch, counted vmcnt ---
  int sl = 0;
  for (int ks = 0; ks < nk - 2; ks++) {
    wait_barrier<PEND>();             // slot ks ready; slot ks+1 in flight
    int s1 = sl + 1; if (s1 == 3) s1 = 0;
    int s2 = s1 + 1; if (s2 == 3) s2 = 0;
    stage(s2, (ks + 2) * BK);         // in flight for ~2 steps
    compute(sl);
    sl = s1;
  }
  {                                   // ks = nk-2: nothing left to stage
    wait_barrier<PEND>();
    int s1 = sl + 1; if (s1 == 3) s1 = 0;
    compute(sl);
    sl = s1;
  }
  wait_barrier<0>();                  // ks = nk-1: drain
  compute(sl);

  // All waves done reading staging slots before ep aliases them.
  __syncthreads();

  // ---- epilogue: per-wave transpose through LDS, full-line b128 stores ----
  // acc[i][j][r] = C(row = wrow*64+i*16+r0+r, col = wcol*64+j*16+fm).
  const int r0  = (lane >> 4) * 4;
  const int err = lane >> 3;          // 0..7
  const int eg  = lane & 7;           // 8-col granule
  float* epw = ep + wv * 16 * 66;
#pragma unroll
  for (int i = 0; i < 4; i++) {
#pragma unroll
    for (int j = 0; j < 4; j++)
#pragma unroll
      for (int r = 0; r < 4; r++)
        epw[(r0 + r) * 66 + j * 16 + fm] = acc[i][j][r];
    // Cross-lane through LDS within the wave: drain DS, pin the schedule.
    asm volatile("s_waitcnt lgkmcnt(0)" ::: "memory");
    __builtin_amdgcn_sched_barrier(0);
#pragma unroll
    for (int s = 0; s < 2; s++) {
      const int rr  = err + s * 8;
      const int m   = mBase + wrow * 64 + i * 16 + rr;
      const int col = n0 + wcol * 64 + eg * 8;
      float p[8];
#pragma unroll
      for (int h = 0; h < 4; h++) {
        f32x2 t = *(const f32x2*)&epw[rr * 66 + eg * 8 + 2 * h];
        p[2 * h]     = t[0];
        p[2 * h + 1] = t[1];
      }
      if (m < M) {
        float bb[8];
        if (MODE != 2) {
          float4 b0v = *(const float4*)(bias + col);
          float4 b1v = *(const float4*)(bias + col + 4);
          bb[0] = b0v.x; bb[1] = b0v.y; bb[2] = b0v.z; bb[3] = b0v.w;
          bb[4] = b1v.x; bb[5] = b1v.y; bb[6] = b1v.z; bb[7] = b1v.w;
        }
        union { u16 u[8]; bf16x8 v; } vl;
        if (MODE == 1) vl.v = *(const bf16x8*)(vLvl + (size_t)m * 512 + col);
        union { u16 u[8]; bf16x8 v; } o;
#pragma unroll
        for (int c = 0; c < 8; c++) {
          float v = p[c];
          if (MODE != 2) v += bb[c];
          if (MODE == 1) v += b2f(vl.u[c]);
          if (MODE != 2) v = v > 0.f ? v : 0.f;
          o.u[c] = f2b(v);
        }
        *(bf16x8*)(out + (size_t)m * 512 + col) = o.v;
      }
    }
    // All lanes finish reading ep before the next i-pass overwrites it
    // (wave-lockstep instruction stream; no cross-wave sharing).
    __builtin_amdgcn_sched_barrier(0);
  }
}

// One launch: convert W_u (512x256) and W_h (512x1536) fp32 -> bf16.
__global__ void cvt_weights(const float* __restrict__ Wu,
                            const float* __restrict__ Wh,
                            u16* __restrict__ Wub, u16* __restrict__ Whb) {
  const int nWu = 512 * 256 / 8;
  const int nWh = 512 * 1536 / 8;
  int i = blockIdx.x * blockDim.x + threadIdx.x;
  const float* src; u16* dst; int c;
  if (i < nWu) { src = Wu; dst = Wub; c = i; }
  else if (i < nWu + nWh) { src = Wh; dst = Whb; c = i - nWu; }
  else return;
  const float4* s = (const float4*)(src + (size_t)c * 8);
  float4 a = s[0], b = s[1];
  union { u16 u[8]; bf16x8 v; } o;
  o.u[0] = f2b(a.x); o.u[1] = f2b(a.y); o.u[2] = f2b(a.z); o.u[3] = f2b(a.w);
  o.u[4] = f2b(b.x); o.u[5] = f2b(b.y); o.u[6] = f2b(b.z); o.u[7] = f2b(b.w);
  *(bf16x8*)(dst + (size_t)c * 8) = o.v;
}

__global__ void cvt_bf16_to_f32(const u16* __restrict__ src, float* __restrict__ dst, int n4) {
  int i = blockIdx.x * blockDim.x + threadIdx.x;
  if (i >= n4) return;
  uint2 p = ((const uint2*)src)[i];
  float4 o;
  o.x = b2f(p.x & 0xffffu); o.y = b2f(p.x >> 16);
  o.z = b2f(p.y & 0xffffu); o.w = b2f(p.y >> 16);
  ((float4*)dst)[i] = o;
}

extern "C" void kernel_launch(void* const* d_in, const int* in_sizes, int n_in,
                              void* d_out, int out_size, void* d_ws, size_t ws_size,
                              hipStream_t stream) {
  const float* contents = (const float*)d_in[0];
  const int2*  children = (const int2*)d_in[1];
  const float* W_u = (const float*)d_in[2];
  const float* b_u = (const float*)d_in[3];
  const float* W_h = (const float*)d_in[4];
  const float* b_h = (const float*)d_in[5];
  float* out = (float*)d_out;

  const int B = 64, D = 11, F = 256, H = 512;
  const int N = B * ((1 << D) - 1);            // 131008
  const int NI = B * ((1 << (D - 1)) - 1);     // 65472

  // Workspace (u16 elems): u_bf [N*512] | v_bf [NI*512] | Wub | Whb.
  // emb ping-pong aliases u's internal rows (dead after the v-GEMM).
  u16* ws16 = (u16*)d_ws;
  u16* u_bf = ws16;
  u16* v_bf = ws16 + (size_t)N * H;
  u16* Wub  = v_bf + (size_t)NI * H;
  u16* Whb  = Wub + 512 * 256;
  u16* embA = u_bf;                            // level-9 dst (32768 rows)
  u16* embB = u_bf + (size_t)32768 * 512;

  // --- weight conversion (single tiny launch) ---
  {
    int n = (512 * 256 + 512 * 1536) / 8;
    cvt_weights<<<(n + 255) / 256, 256, 0, stream>>>(W_u, W_h, Wub, Whb);
  }

  // --- GEMM1: u = relu(contents @ W_u^T + b_u) ---
  {
    int mb = (N + 127) / 128;                  // 1024
    gemm_db<0><<<mb * 4, 256, 0, stream>>>(contents, nullptr, nullptr, nullptr,
                                           nullptr, Wub, F, b_u, u_bf, N, F, mb);
  }

  // --- v-GEMM: v = u[0:NI] @ W_hu^T (W_h cols 1024..1535 in place) ---
  {
    int mb = (NI + 127) / 128;                 // 512
    gemm_db<2><<<mb * 4, 256, 0, stream>>>(nullptr, u_bf, nullptr, nullptr,
                                           nullptr, Whb + 1024, 3 * H, nullptr,
                                           v_bf, NI, H, mb);
  }

  // --- tree levels j = D-2 .. 0 (K=1024 children; v in epilogue) ---
  const u16* embPrev = u_bf + (size_t)NI * H;  // leaves = u[NI:]
  u16* dst = embA;
  for (int j = D - 2; j >= 0; --j) {
    int M = B << j;
    int o = B * ((1 << j) - 1);
    int mb = (M + 127) / 128;
    gemm_db<1><<<mb * 4, 256, 0, stream>>>(nullptr, nullptr, embPrev,
                                           children + o, v_bf + (size_t)o * H,
                                           Whb, 3 * H, b_h, dst, M, 2 * H, mb);
    embPrev = dst;
    dst = (dst == embA) ? embB : embA;
  }

  // --- level-0 emb (64 x 512) -> fp32 output ---
  {
    int n4 = B * H / 4;
    cvt_bf16_to_f32<<<(n4 + 255) / 256, 256, 0, stream>>>(embPrev, out, n4);
  }
}

// Round 6
// 520.505 us; speedup vs baseline: 1.5513x; 1.0246x over previous
//
#include <hip/hip_runtime.h>
#include <hip/hip_bf16.h>

// RecNN: u = relu(contents @ W_u^T + b_u); v = u[internal] @ W_hu^T (hoisted);
// 10 levels emb = relu([emb_L|emb_R] @ W_LR^T + v + b_h).
//
// Round-10:
//  - MODE 1/2 (levels, v-GEMM): unchanged R9 structure (3-slot LDS rotation,
//    counted vmcnt(4), stage-after-barrier, XOR granule swizzle, coalesced
//    epilogue) -- proven: total dropped 598 -> 533 when these pipelined.
//  - GEMM1: new dedicated kernel gemm1_k64. R9's fp32-in-LDS MODE0 regressed
//    (136 us: 72KB LDS -> 2 blk/CU, cvt on fragment path, +4.2M conflicts).
//    Diagnosis across R4-R9: at BK=32 a k-step is ~250-300cy of work, so even
//    depth-2 prefetch can't cover the ~600-900cy L3/HBM latency of the
//    contents stream at 8-12 waves/CU. Fix = BK=64: 32 MFMA+16 ds_read per
//    step (~500+cy) so the R8-proven depth-1 reg-staged schedule covers the
//    latency; K=256 -> just 4 k-steps. Full 3-bit granule XOR swizzle
//    (g ^ (row&7), 8 granules/row) on A-write/A-read/B-glds-source, checked
//    conflict-free per 8-lane b128 batch. LDS 64KB -> 2 blk/CU, so VGPR up
//    to 256 is free (reg staging can't spill us below the LDS-set occupancy).

typedef unsigned short u16;
typedef __attribute__((ext_vector_type(8))) short bf16x8;
typedef __attribute__((ext_vector_type(4))) float f32x4;
typedef __attribute__((ext_vector_type(2))) float f32x2;

#define BK 32

__device__ __forceinline__ u16 f2b(float f) {
  union { float f; unsigned u; } c; c.f = f;
  unsigned u = c.u;
  return (u16)((u + 0x7fffu + ((u >> 16) & 1u)) >> 16);  // RNE
}

__device__ __forceinline__ float b2f(unsigned hi16) {
  union { float f; unsigned u; } c; c.u = hi16 << 16; return c.f;
}

__device__ __forceinline__ void glds16(const void* g, void* l) {
  __builtin_amdgcn_global_load_lds(
      (__attribute__((address_space(1))) void*)g,
      (__attribute__((address_space(3))) void*)l, 16, 0, 0);
}

template <int N>
__device__ __forceinline__ void wait_barrier() {
  asm volatile("s_waitcnt vmcnt(%0) lgkmcnt(0)" :: "n"(N) : "memory");
  __builtin_amdgcn_s_barrier();
  asm volatile("" ::: "memory");
}

// ---------------------------------------------------------------------------
// GEMM1: u = relu(contents[M][256] @ W_u^T + b_u), out bf16 [M][512].
// BK=64, 2-buffer, reg-staged fp32->bf16 A, glds B, coalesced epilogue.
// ---------------------------------------------------------------------------
__global__ __launch_bounds__(256, 2)
void gemm1_k64(const float* __restrict__ A,      // [M][256] fp32
               const u16* __restrict__ W,        // Wub bf16 [512][256]
               const float* __restrict__ bias,
               u16* __restrict__ out,            // [M][512] bf16
               int M, int nBlkM) {
  constexpr int KK = 256, BK64 = 64, NK = KK / BK64;   // 4 steps
  __shared__ __align__(16) char pool[65536];           // 2x16KB A + 2x16KB B
  auto lA = [&](int s) { return (u16*)(pool + s * 16384); };
  auto lB = [&](int s) { return (u16*)(pool + 32768 + s * 16384); };
  float* ep = (float*)pool;   // epilogue transpose alias (16.9 KB, after sync)

  const int tid  = threadIdx.x;
  const int lane = tid & 63;
  const int wv   = tid >> 6;
  const int wrow = wv >> 1, wcol = wv & 1;

  int mb, nb;
  {
    int b = blockIdx.x;
    if ((nBlkM & 7) == 0) {
      int xcd = b & 7;
      nb = (b >> 3) & 3;
      mb = ((b >> 5) << 3) | xcd;
    } else { nb = b & 3; mb = b >> 2; }
  }
  const int mBase = mb * 128;
  const int n0    = nb * 128;

  // A staging: thread covers rows r0s, r0s+64, cols q*16..+15 (2 granules).
  const int r0s = tid >> 2, q = tid & 3;
  const float *a0p, *a1p;
  {
    int m0 = min(mBase + r0s, M - 1);
    int m1 = min(mBase + r0s + 64, M - 1);
    a0p = A + (size_t)m0 * KK + q * 16;
    a1p = A + (size_t)m1 * KK + q * 16;
  }
  const int ph0 = (2 * q) ^ (r0s & 7);   // phys granule of logical 2q; ^1 for 2q+1

  // B staging via glds: per wave 4 issues of 1KB (8 rows x 8 granules).
  const int rB  = wv * 32 + (lane >> 3);               // +t*8
  const int swB = ((lane & 7) ^ ((lane >> 3) & 7)) * 8;  // preswizzled src col
  const u16* bpp = W + (size_t)(n0 + rB) * 256 + swB;
  const int dB = rB * 64 + (lane & 7) * 8;             // +t*512 (lane-linear)

  f32x4 acc[4][4] = {};
  const int fm = lane & 15, ql = lane >> 4;

  auto stageB = [&](int s, int k0) {
#pragma unroll
    for (int t = 0; t < 4; t++)
      glds16(bpp + (size_t)t * 8 * 256 + k0, lB(s) + dB + t * 512);
  };
  float4 rg[8];
  auto loadA = [&](int k0) {
    const float4* s0 = (const float4*)(a0p + k0);
    const float4* s1 = (const float4*)(a1p + k0);
    rg[0] = s0[0]; rg[1] = s0[1]; rg[2] = s0[2]; rg[3] = s0[3];
    rg[4] = s1[0]; rg[5] = s1[1]; rg[6] = s1[2]; rg[7] = s1[3];
  };
  auto cvtA = [&](int s) {
    u16* Ab = lA(s);
#pragma unroll
    for (int h = 0; h < 2; h++) {
      const int r = r0s + h * 64;
      float4 x = rg[h * 4 + 0], y = rg[h * 4 + 1];
      float4 z = rg[h * 4 + 2], w = rg[h * 4 + 3];
      union { __hip_bfloat162 hh[4]; bf16x8 v; } o1, o2;
      o1.hh[0] = __float22bfloat162_rn({x.x, x.y});
      o1.hh[1] = __float22bfloat162_rn({x.z, x.w});
      o1.hh[2] = __float22bfloat162_rn({y.x, y.y});
      o1.hh[3] = __float22bfloat162_rn({y.z, y.w});
      o2.hh[0] = __float22bfloat162_rn({z.x, z.y});
      o2.hh[1] = __float22bfloat162_rn({z.z, z.w});
      o2.hh[2] = __float22bfloat162_rn({w.x, w.y});
      o2.hh[3] = __float22bfloat162_rn({w.z, w.w});
      *(bf16x8*)&Ab[r * 64 + ph0 * 8]       = o1.v;   // logical granule 2q
      *(bf16x8*)&Ab[r * 64 + (ph0 ^ 1) * 8] = o2.v;   // logical granule 2q+1
    }
  };
  auto compute64 = [&](int s) {
    const u16* Ab = lA(s);
    const u16* Bb = lB(s);
    __builtin_amdgcn_s_setprio(1);
#pragma unroll
    for (int kk = 0; kk < 2; kk++) {
      bf16x8 av[4], bv[4];
#pragma unroll
      for (int i = 0; i < 4; i++) {
        const int ra = wrow * 64 + i * 16 + fm;
        const int rb = wcol * 64 + i * 16 + fm;
        const int pg = ((kk * 4 + ql) ^ (fm & 7)) * 8;
        av[i] = *(const bf16x8*)&Ab[ra * 64 + pg];
        bv[i] = *(const bf16x8*)&Bb[rb * 64 + pg];
      }
#pragma unroll
      for (int i = 0; i < 4; i++)
#pragma unroll
        for (int j = 0; j < 4; j++)
          acc[i][j] = __builtin_amdgcn_mfma_f32_16x16x32_bf16(av[i], bv[j], acc[i][j], 0, 0, 0);
    }
    __builtin_amdgcn_s_setprio(0);
  };

  // prologue
  loadA(0);
  stageB(0, 0);
  cvtA(0);
  for (int ks = 0; ks < NK; ks++) {
    const int cur = ks & 1, nxt = cur ^ 1;
    __syncthreads();
    const bool more = (ks + 1 < NK);
    if (more) {
      loadA((ks + 1) * BK64);          // regs in flight under the MFMA stage
      stageB(nxt, (ks + 1) * BK64);    // glds in flight until next barrier
    }
    compute64(cur);
    if (more) cvtA(nxt);
  }
  __syncthreads();                     // staging dead before ep aliases it

  // epilogue: per-wave transpose through LDS, full-line b128 stores
  const int r0  = (lane >> 4) * 4;
  const int err = lane >> 3;
  const int eg  = lane & 7;
  float* epw = ep + wv * 16 * 66;
#pragma unroll
  for (int i = 0; i < 4; i++) {
#pragma unroll
    for (int j = 0; j < 4; j++)
#pragma unroll
      for (int r = 0; r < 4; r++)
        epw[(r0 + r) * 66 + j * 16 + fm] = acc[i][j][r];
    asm volatile("s_waitcnt lgkmcnt(0)" ::: "memory");
    __builtin_amdgcn_sched_barrier(0);
#pragma unroll
    for (int s = 0; s < 2; s++) {
      const int rr  = err + s * 8;
      const int m   = mBase + wrow * 64 + i * 16 + rr;
      const int col = n0 + wcol * 64 + eg * 8;
      float p[8];
#pragma unroll
      for (int h = 0; h < 4; h++) {
        f32x2 t = *(const f32x2*)&epw[rr * 66 + eg * 8 + 2 * h];
        p[2 * h] = t[0]; p[2 * h + 1] = t[1];
      }
      if (m < M) {
        float4 b0v = *(const float4*)(bias + col);
        float4 b1v = *(const float4*)(bias + col + 4);
        float bb[8] = {b0v.x, b0v.y, b0v.z, b0v.w, b1v.x, b1v.y, b1v.z, b1v.w};
        union { u16 u[8]; bf16x8 v; } o;
#pragma unroll
        for (int c = 0; c < 8; c++) {
          float v = p[c] + bb[c];
          o.u[c] = f2b(v > 0.f ? v : 0.f);
        }
        *(bf16x8*)(out + (size_t)m * 512 + col) = o.v;
      }
    }
    __builtin_amdgcn_sched_barrier(0);
  }
}

// ---------------------------------------------------------------------------
// MODE 2: A bf16 [M][K], raw store                               (v-GEMM)
// MODE 1: A gathered [emb[c.x] | emb[c.y]] (K=1024), +v+bias+relu (levels)
// R9 structure: 3-slot rotation, counted vmcnt(4), coalesced epilogue.
// ---------------------------------------------------------------------------
template <int MODE>
__global__ __launch_bounds__(256, 3)
void gemm_db(const u16* __restrict__ Abf,
             const u16* __restrict__ embPrev,
             const int2* __restrict__ idx,
             const u16* __restrict__ vLvl,   // [M][512] bf16
             const u16* __restrict__ W,      // bf16, row stride ldb (B^T)
             int ldb,
             const float* __restrict__ bias,
             u16* __restrict__ out,          // [M][512] bf16
             int M, int K, int nBlkM) {
  __shared__ __align__(16) char pool[6 * 8192];
  auto lAb = [&](int s) { return (u16*)(pool + s * 8192); };
  auto lBp = [&](int s) { return (u16*)(pool + 3 * 8192 + s * 8192); };
  float* ep = (float*)pool;   // epilogue transpose alias (16.9 KB, after sync)

  const int tid  = threadIdx.x;
  const int lane = tid & 63;
  const int wv   = tid >> 6;
  const int wrow = wv >> 1, wcol = wv & 1;

  int mb, nb;
  {
    int b = blockIdx.x;
    if ((nBlkM & 7) == 0) {
      int xcd = b & 7;
      nb = (b >> 3) & 3;
      mb = ((b >> 5) << 3) | xcd;
    } else { nb = b & 3; mb = b >> 2; }
  }
  const int mBase = mb * 128;
  const int n0    = nb * 128;

  const int rowA0 = tid >> 2;
  const int colq  = ((tid & 3) ^ ((tid >> 3) & 3)) * 8;

  const u16 *ab0 = nullptr, *ab1 = nullptr;
  const u16 *aL0 = nullptr, *aR0 = nullptr, *aL1 = nullptr, *aR1 = nullptr;
  {
    int m0 = min(mBase + rowA0, M - 1);
    int m1 = min(mBase + rowA0 + 64, M - 1);
    if (MODE == 2) {
      ab0 = Abf + (size_t)m0 * K + colq;
      ab1 = Abf + (size_t)m1 * K + colq;
    } else {
      int2 c0 = idx[m0], c1 = idx[m1];
      aL0 = embPrev + (size_t)c0.x * 512 + colq;
      aR0 = embPrev + (size_t)c0.y * 512 + colq;
      aL1 = embPrev + (size_t)c1.x * 512 + colq;
      aR1 = embPrev + (size_t)c1.y * 512 + colq;
    }
  }
  const u16* bp0 = W + (size_t)(n0 + rowA0) * ldb + colq;
  const u16* bp1 = W + (size_t)(n0 + rowA0 + 64) * ldb + colq;

  f32x4 acc[4][4] = {};
  const int fm  = lane & 15;
  const int q   = lane >> 4;
  const int gs8 = (q ^ ((fm >> 1) & 3)) * 8;
  const int nk  = K / BK;

  auto stage = [&](int s, int k0) {
    if (MODE == 2) {
      glds16(ab0 + k0, lAb(s) + tid * 8);
      glds16(ab1 + k0, lAb(s) + (tid + 256) * 8);
    } else {  // gather; colq < 32 elems never flips the L/R bit
      const u16* g0 = ((k0 & 512) ? aR0 : aL0) + (k0 & 511);
      const u16* g1 = ((k0 & 512) ? aR1 : aL1) + (k0 & 511);
      glds16(g0, lAb(s) + tid * 8);
      glds16(g1, lAb(s) + (tid + 256) * 8);
    }
    glds16(bp0 + k0, lBp(s) + tid * 8);
    glds16(bp1 + k0, lBp(s) + (tid + 256) * 8);
  };

  auto compute = [&](int s) {
    bf16x8 av[4], bv[4];
    const u16* Ab = lAb(s);
    const u16* Bb = lBp(s);
#pragma unroll
    for (int i = 0; i < 4; i++) {
      av[i] = *(const bf16x8*)&Ab[(wrow * 64 + i * 16 + fm) * BK + gs8];
      bv[i] = *(const bf16x8*)&Bb[(wcol * 64 + i * 16 + fm) * BK + gs8];
    }
    __builtin_amdgcn_s_setprio(1);
#pragma unroll
    for (int i = 0; i < 4; i++)
#pragma unroll
      for (int j = 0; j < 4; j++)
        acc[i][j] = __builtin_amdgcn_mfma_f32_16x16x32_bf16(av[i], bv[j], acc[i][j], 0, 0, 0);
    __builtin_amdgcn_s_setprio(0);
  };

  stage(0, 0);
  asm volatile("" ::: "memory");
  stage(1, BK);

  int sl = 0;
  for (int ks = 0; ks < nk - 2; ks++) {
    wait_barrier<4>();
    int s1 = sl + 1; if (s1 == 3) s1 = 0;
    int s2 = s1 + 1; if (s2 == 3) s2 = 0;
    stage(s2, (ks + 2) * BK);
    compute(sl);
    sl = s1;
  }
  {
    wait_barrier<4>();
    int s1 = sl + 1; if (s1 == 3) s1 = 0;
    compute(sl);
    sl = s1;
  }
  wait_barrier<0>();
  compute(sl);

  __syncthreads();

  const int r0  = (lane >> 4) * 4;
  const int err = lane >> 3;
  const int eg  = lane & 7;
  float* epw = ep + wv * 16 * 66;
#pragma unroll
  for (int i = 0; i < 4; i++) {
#pragma unroll
    for (int j = 0; j < 4; j++)
#pragma unroll
      for (int r = 0; r < 4; r++)
        epw[(r0 + r) * 66 + j * 16 + fm] = acc[i][j][r];
    asm volatile("s_waitcnt lgkmcnt(0)" ::: "memory");
    __builtin_amdgcn_sched_barrier(0);
#pragma unroll
    for (int s = 0; s < 2; s++) {
      const int rr  = err + s * 8;
      const int m   = mBase + wrow * 64 + i * 16 + rr;
      const int col = n0 + wcol * 64 + eg * 8;
      float p[8];
#pragma unroll
      for (int h = 0; h < 4; h++) {
        f32x2 t = *(const f32x2*)&epw[rr * 66 + eg * 8 + 2 * h];
        p[2 * h] = t[0]; p[2 * h + 1] = t[1];
      }
      if (m < M) {
        float bb[8];
        if (MODE != 2) {
          float4 b0v = *(const float4*)(bias + col);
          float4 b1v = *(const float4*)(bias + col + 4);
          bb[0] = b0v.x; bb[1] = b0v.y; bb[2] = b0v.z; bb[3] = b0v.w;
          bb[4] = b1v.x; bb[5] = b1v.y; bb[6] = b1v.z; bb[7] = b1v.w;
        }
        union { u16 u[8]; bf16x8 v; } vl;
        if (MODE == 1) vl.v = *(const bf16x8*)(vLvl + (size_t)m * 512 + col);
        union { u16 u[8]; bf16x8 v; } o;
#pragma unroll
        for (int c = 0; c < 8; c++) {
          float v = p[c];
          if (MODE != 2) v += bb[c];
          if (MODE == 1) v += b2f(vl.u[c]);
          if (MODE != 2) v = v > 0.f ? v : 0.f;
          o.u[c] = f2b(v);
        }
        *(bf16x8*)(out + (size_t)m * 512 + col) = o.v;
      }
    }
    __builtin_amdgcn_sched_barrier(0);
  }
}

// One launch: convert W_u (512x256) and W_h (512x1536) fp32 -> bf16.
__global__ void cvt_weights(const float* __restrict__ Wu,
                            const float* __restrict__ Wh,
                            u16* __restrict__ Wub, u16* __restrict__ Whb) {
  const int nWu = 512 * 256 / 8;
  const int nWh = 512 * 1536 / 8;
  int i = blockIdx.x * blockDim.x + threadIdx.x;
  const float* src; u16* dst; int c;
  if (i < nWu) { src = Wu; dst = Wub; c = i; }
  else if (i < nWu + nWh) { src = Wh; dst = Whb; c = i - nWu; }
  else return;
  const float4* s = (const float4*)(src + (size_t)c * 8);
  float4 a = s[0], b = s[1];
  union { u16 u[8]; bf16x8 v; } o;
  o.u[0] = f2b(a.x); o.u[1] = f2b(a.y); o.u[2] = f2b(a.z); o.u[3] = f2b(a.w);
  o.u[4] = f2b(b.x); o.u[5] = f2b(b.y); o.u[6] = f2b(b.z); o.u[7] = f2b(b.w);
  *(bf16x8*)(dst + (size_t)c * 8) = o.v;
}

__global__ void cvt_bf16_to_f32(const u16* __restrict__ src, float* __restrict__ dst, int n4) {
  int i = blockIdx.x * blockDim.x + threadIdx.x;
  if (i >= n4) return;
  uint2 p = ((const uint2*)src)[i];
  float4 o;
  o.x = b2f(p.x & 0xffffu); o.y = b2f(p.x >> 16);
  o.z = b2f(p.y & 0xffffu); o.w = b2f(p.y >> 16);
  ((float4*)dst)[i] = o;
}

extern "C" void kernel_launch(void* const* d_in, const int* in_sizes, int n_in,
                              void* d_out, int out_size, void* d_ws, size_t ws_size,
                              hipStream_t stream) {
  const float* contents = (const float*)d_in[0];
  const int2*  children = (const int2*)d_in[1];
  const float* W_u = (const float*)d_in[2];
  const float* b_u = (const float*)d_in[3];
  const float* W_h = (const float*)d_in[4];
  const float* b_h = (const float*)d_in[5];
  float* out = (float*)d_out;

  const int B = 64, D = 11, F = 256, H = 512;
  const int N = B * ((1 << D) - 1);            // 131008
  const int NI = B * ((1 << (D - 1)) - 1);     // 65472

  // Workspace (u16 elems): u_bf [N*512] | v_bf [NI*512] | Wub | Whb.
  u16* ws16 = (u16*)d_ws;
  u16* u_bf = ws16;
  u16* v_bf = ws16 + (size_t)N * H;
  u16* Wub  = v_bf + (size_t)NI * H;
  u16* Whb  = Wub + 512 * 256;
  u16* embA = u_bf;                            // level-9 dst (32768 rows)
  u16* embB = u_bf + (size_t)32768 * 512;

  // --- weight conversion (single tiny launch) ---
  {
    int n = (512 * 256 + 512 * 1536) / 8;
    cvt_weights<<<(n + 255) / 256, 256, 0, stream>>>(W_u, W_h, Wub, Whb);
  }

  // --- GEMM1: u = relu(contents @ W_u^T + b_u) ---
  {
    int mb = (N + 127) / 128;                  // 1024
    gemm1_k64<<<mb * 4, 256, 0, stream>>>(contents, Wub, b_u, u_bf, N, mb);
  }

  // --- v-GEMM: v = u[0:NI] @ W_hu^T (W_h cols 1024..1535 in place) ---
  {
    int mb = (NI + 127) / 128;                 // 512
    gemm_db<2><<<mb * 4, 256, 0, stream>>>(u_bf, nullptr, nullptr,
                                           nullptr, Whb + 1024, 3 * H, nullptr,
                                           v_bf, NI, H, mb);
  }

  // --- tree levels j = D-2 .. 0 (K=1024 children; v in epilogue) ---
  const u16* embPrev = u_bf + (size_t)NI * H;  // leaves = u[NI:]
  u16* dst = embA;
  for (int j = D - 2; j >= 0; --j) {
    int M = B << j;
    int o = B * ((1 << j) - 1);
    int mb = (M + 127) / 128;
    gemm_db<1><<<mb * 4, 256, 0, stream>>>(nullptr, embPrev,
                                           children + o, v_bf + (size_t)o * H,
                                           Whb, 3 * H, b_h, dst, M, 2 * H, mb);
    embPrev = dst;
    dst = (dst == embA) ? embB : embA;
  }

  // --- level-0 emb (64 x 512) -> fp32 output ---
  {
    int n4 = B * H / 4;
    cvt_bf16_to_f32<<<(n4 + 255) / 256, 256, 0, stream>>>(embPrev, out, n4);
  }
}